// Round 1
// baseline (464.802 us; speedup 1.0000x reference)
//
#include <hip/hip_runtime.h>

#define DIM 64
#define EPS 1e-8f
#define ALPHA_T 0.1f

// One wave per node: lane d loads embs[node][d], 6-step shfl reduce -> inv_norm.
__global__ void norm_kernel(const float* __restrict__ embs,
                            float* __restrict__ inv_norm, int n_nodes) {
    int wave = (blockIdx.x * blockDim.x + threadIdx.x) >> 6;
    int lane = threadIdx.x & 63;
    if (wave >= n_nodes) return;
    float v = embs[wave * DIM + lane];
    float ss = v * v;
    #pragma unroll
    for (int m = 32; m >= 1; m >>= 1) ss += __shfl_xor(ss, m);
    if (lane == 0) {
        inv_norm[wave] = 1.0f / fmaxf(sqrtf(ss), EPS);
    }
}

// One wave per edge. Fused: cosine-refine the edge weight, then scatter-add
// refined * x[col] into out[row]. For the first SpMM x == embs (reuse the
// already-loaded tar row t); for the second x == msg_tar.
__global__ void refine_spmm_kernel(const float* __restrict__ embs,
                                   const float* __restrict__ x,
                                   const int* __restrict__ eidx,
                                   const float* __restrict__ eval_,
                                   const float* __restrict__ inv_norm,
                                   float* __restrict__ out,
                                   int n_edges) {
    int wave = (blockIdx.x * blockDim.x + threadIdx.x) >> 6;
    int lane = threadIdx.x & 63;
    if (wave >= n_edges) return;

    int r0 = eidx[wave];            // row (scatter target), also "src" emb
    int r1 = eidx[n_edges + wave];  // col (gather source), also "tar" emb

    float s = embs[r0 * DIM + lane];
    float t = embs[r1 * DIM + lane];
    float dot = s * t;
    #pragma unroll
    for (int m = 32; m >= 1; m >>= 1) dot += __shfl_xor(dot, m);

    float sim = dot * inv_norm[r0] * inv_norm[r1];
    float sim_norm = fminf(fmaxf((sim + 1.0f) * 0.5f, 0.0f), 1.0f);
    float refined = eval_[wave] * (1.0f + ALPHA_T * sim_norm);

    float xv = (x == embs) ? t : x[r1 * DIM + lane];
    atomicAdd(&out[r0 * DIM + lane], refined * xv);
}

extern "C" void kernel_launch(void* const* d_in, const int* in_sizes, int n_in,
                              void* d_out, int out_size, void* d_ws, size_t ws_size,
                              hipStream_t stream) {
    const float* embs    = (const float*)d_in[0];
    const int*   src_idx = (const int*)d_in[1];
    const float* src_val = (const float*)d_in[2];
    const int*   tar_idx = (const int*)d_in[3];
    const float* tar_val = (const float*)d_in[4];
    float* out = (float*)d_out;

    int n_nodes = in_sizes[0] / DIM;
    int n_edges = in_sizes[2];

    float* inv_norm = (float*)d_ws;              // n_nodes floats (200 KB)
    float* msg_tar  = inv_norm + n_nodes;        // n_nodes*DIM floats (12.8 MB)

    // Accumulators must start at zero (ws/out are poisoned to 0xAA).
    hipMemsetAsync(msg_tar, 0, (size_t)n_nodes * DIM * sizeof(float), stream);
    hipMemsetAsync(d_out, 0, (size_t)out_size * sizeof(float), stream);

    norm_kernel<<<(n_nodes + 3) / 4, 256, 0, stream>>>(embs, inv_norm, n_nodes);

    // SpMM 1: msg_tar = A_tar(refined) @ embs
    refine_spmm_kernel<<<(n_edges + 3) / 4, 256, 0, stream>>>(
        embs, embs, tar_idx, tar_val, inv_norm, msg_tar, n_edges);

    // SpMM 2: out = A_src(refined) @ msg_tar
    refine_spmm_kernel<<<(n_edges + 3) / 4, 256, 0, stream>>>(
        embs, msg_tar, src_idx, src_val, inv_norm, out, n_edges);
}